// Round 10
// baseline (58.898 us; speedup 1.0000x reference)
//
#include <hip/hip_runtime.h>
#include <hip/hip_bf16.h>

#define BATCH 8
#define V 2048
#define H 256
#define D 128

typedef __attribute__((ext_vector_type(8))) _Float16 f16x8;
typedef __attribute__((ext_vector_type(4))) float f32x4;
typedef unsigned int uint32;

static __device__ __forceinline__ uint32 pk2(float lo, float hi) {
  __fp16 __attribute__((ext_vector_type(2))) h = __builtin_amdgcn_cvt_pkrtz(lo, hi);
  uint32 u;
  __builtin_memcpy(&u, &h, 4);
  return u;
}

// -------- K_pack: adj -> bitmask words [V][64]; blk==V computes vL/vR = W^T aL/aR --------
__global__ __launch_bounds__(256) void k_pack(const int* __restrict__ adj,
                                              const float* __restrict__ W,
                                              const float* __restrict__ a,
                                              unsigned int* __restrict__ pk,
                                              float* __restrict__ vL,
                                              float* __restrict__ vR) {
  const int blk = blockIdx.x;
  if (blk < V) {
    const int w = threadIdx.x >> 6, lane = threadIdx.x & 63;
    const int* row = adj + (size_t)blk * V;
#pragma unroll
    for (int it = 0; it < 8; ++it) {
      const int j = it * 256 + w * 64 + lane;
      unsigned long long m = __ballot(row[j] != 0);
      if (lane < 2)
        pk[blk * 64 + it * 8 + w * 2 + lane] = (unsigned int)(m >> (lane * 32));
    }
  } else {
    const int h = threadIdx.x;  // 0..255
    float sL = 0.f, sR = 0.f;
    for (int d = 0; d < D; ++d) {
      const float wv = W[(size_t)d * H + h];
      sL += wv * a[d];
      sR += wv * a[D + d];
    }
    vL[h] = sL;
    vR[h] = sR;
  }
}

// -------- K_proj: p = x @ W^T via f16 MFMA (fp32 acc); e from x.(W^T a) in fp32;
//          f16 fragment store to pTf --------
// block: 32 j-rows x 128 d; wave handles d rows [wave*32, wave*32+32) (2 dt tiles).
#define DOT4(s, xv, vv) \
  s += (xv).x * (vv).x + (xv).y * (vv).y + (xv).z * (vv).z + (xv).w * (vv).w;

__global__ __launch_bounds__(256, 2) void k_proj(const float* __restrict__ x,
                                                 const float* __restrict__ W,
                                                 const float* __restrict__ vL,
                                                 const float* __restrict__ vR,
                                                 _Float16* __restrict__ pTf,
                                                 float* __restrict__ ei,
                                                 _Float16* __restrict__ Fh,
                                                 _Float16* __restrict__ Ph) {
  __shared__ _Float16 st[128][52];  // 13 KB
  const int t = threadIdx.x, lane = t & 63, wave = t >> 6;
  const int b = blockIdx.x >> 6;
  const int j0 = (blockIdx.x & 63) * 32;
  const int kq = lane >> 4, l15 = lane & 15;

  const float* wrow0 = W + (size_t)(wave * 32 + l15) * H + kq * 8;      // dt0
  const float* wrow1 = wrow0 + 16 * H;                                   // dt1
  const float* xrow0 = x + ((size_t)(b * V + j0 + l15)) * H + kq * 8;    // jt0
  const float* xrow1 = xrow0 + 16 * H;                                   // jt1
  const float* vLp = vL + kq * 8;
  const float* vRp = vR + kq * 8;

  f32x4 acc[2][2];
#pragma unroll
  for (int i_ = 0; i_ < 2; ++i_)
#pragma unroll
    for (int j_ = 0; j_ < 2; ++j_) acc[i_][j_] = (f32x4){0.f, 0.f, 0.f, 0.f};
  float eL0 = 0.f, eL1 = 0.f, eR0 = 0.f, eR1 = 0.f;

  typedef union { uint32 u[4]; f16x8 v; } AFu;
#pragma unroll
  for (int ks = 0; ks < 8; ++ks) {
    const int ho = ks * 32;
    const float4 w0a = *(const float4*)(wrow0 + ho), w0b = *(const float4*)(wrow0 + ho + 4);
    const float4 w1a = *(const float4*)(wrow1 + ho), w1b = *(const float4*)(wrow1 + ho + 4);
    const float4 x0a = *(const float4*)(xrow0 + ho), x0b = *(const float4*)(xrow0 + ho + 4);
    const float4 x1a = *(const float4*)(xrow1 + ho), x1b = *(const float4*)(xrow1 + ho + 4);
    AFu aw0, aw1, bx0, bx1;
    aw0.u[0] = pk2(w0a.x, w0a.y); aw0.u[1] = pk2(w0a.z, w0a.w);
    aw0.u[2] = pk2(w0b.x, w0b.y); aw0.u[3] = pk2(w0b.z, w0b.w);
    aw1.u[0] = pk2(w1a.x, w1a.y); aw1.u[1] = pk2(w1a.z, w1a.w);
    aw1.u[2] = pk2(w1b.x, w1b.y); aw1.u[3] = pk2(w1b.z, w1b.w);
    bx0.u[0] = pk2(x0a.x, x0a.y); bx0.u[1] = pk2(x0a.z, x0a.w);
    bx0.u[2] = pk2(x0b.x, x0b.y); bx0.u[3] = pk2(x0b.z, x0b.w);
    bx1.u[0] = pk2(x1a.x, x1a.y); bx1.u[1] = pk2(x1a.z, x1a.w);
    bx1.u[2] = pk2(x1b.x, x1b.y); bx1.u[3] = pk2(x1b.z, x1b.w);
    acc[0][0] = __builtin_amdgcn_mfma_f32_16x16x32_f16(aw0.v, bx0.v, acc[0][0], 0, 0, 0);
    acc[0][1] = __builtin_amdgcn_mfma_f32_16x16x32_f16(aw0.v, bx1.v, acc[0][1], 0, 0, 0);
    acc[1][0] = __builtin_amdgcn_mfma_f32_16x16x32_f16(aw1.v, bx0.v, acc[1][0], 0, 0, 0);
    acc[1][1] = __builtin_amdgcn_mfma_f32_16x16x32_f16(aw1.v, bx1.v, acc[1][1], 0, 0, 0);
    if (wave == 0) {  // fp32 e-partials from the same x registers
      const float4 vla = *(const float4*)(vLp + ho), vlb = *(const float4*)(vLp + ho + 4);
      const float4 vra = *(const float4*)(vRp + ho), vrb = *(const float4*)(vRp + ho + 4);
      DOT4(eL0, x0a, vla) DOT4(eL0, x0b, vlb)
      DOT4(eL1, x1a, vla) DOT4(eL1, x1b, vlb)
      DOT4(eR0, x0a, vra) DOT4(eR0, x0b, vrb)
      DOT4(eR1, x1a, vra) DOT4(eR1, x1b, vrb)
    }
  }

  if (wave == 0) {  // reduce e over kq lanes; lanes 0..15 write
    eL0 += __shfl_xor(eL0, 16, 64); eL0 += __shfl_xor(eL0, 32, 64);
    eL1 += __shfl_xor(eL1, 16, 64); eL1 += __shfl_xor(eL1, 32, 64);
    eR0 += __shfl_xor(eR0, 16, 64); eR0 += __shfl_xor(eR0, 32, 64);
    eR1 += __shfl_xor(eR1, 16, 64); eR1 += __shfl_xor(eR1, 32, 64);
    if (lane < 16) {
      const size_t r0 = (size_t)b * V + j0 + lane;
      ei[r0] = eL0;
      Fh[r0] = (_Float16)__expf(eR0);
      Ph[r0] = (_Float16)__expf(0.2f * eR0);
      const size_t r1 = r0 + 16;
      ei[r1] = eL1;
      Fh[r1] = (_Float16)__expf(eR1);
      Ph[r1] = (_Float16)__expf(0.2f * eR1);
    }
  }

  // C regs -> st[d][j] (f16 transpose staging)
#pragma unroll
  for (int t_ = 0; t_ < 2; ++t_)
#pragma unroll
    for (int jt = 0; jt < 2; ++jt)
#pragma unroll
      for (int r = 0; r < 4; ++r)
        st[(wave * 2 + t_) * 16 + kq * 4 + r][jt * 16 + l15] = (_Float16)acc[t_][jt][r];
  __syncthreads();

  // fragment store: pTf[b][c][dt][ks][lane][8]
  const int c = (blockIdx.x & 63) >> 1;
  const int ks = blockIdx.x & 1;
  const int g = t >> 6;
#pragma unroll
  for (int ff = 0; ff < 2; ++ff) {
    const int dt = ff * 4 + g;
    const int dR = dt * 16 + l15;
    const int jc = kq * 8;
    union { unsigned long long ll[2]; f16x8 v; } vv_;
    vv_.ll[0] = *(const unsigned long long*)&st[dR][jc];
    vv_.ll[1] = *(const unsigned long long*)&st[dR][jc + 4];
    *(f16x8*)((char*)pTf +
              (((((size_t)b * 32 + c) * 8 + dt) * 2 + ks) * 64 + lane) * 16) = vv_.v;
  }
}

// -------- K_attn: out = relu((w @ p) / rowsum), f16 MFMA, chain-split accs --------
// (unchanged from passing R9 kernel)

typedef union { uint4 v; uint32 u[4]; } U4;
typedef union { uint32 u[4]; f16x8 v; } AFu;
struct PFS {
  U4 FH0, FH1, PH0, PH1, M0, M1;
  AFu AF0, AF1;
  uint32 w0, w1;
};

#define PKMUL(d, a, b) asm("v_pk_mul_f16 %0, %1, %2" : "=v"(d) : "v"(a), "v"(b));
#define PKMAX(d, a, b) asm("v_pk_max_f16 %0, %1, %2" : "=v"(d) : "v"(a), "v"(b));

#define WGEN1(AF, FH_, PH_, MSK_)                        \
  {                                                      \
    _Pragma("unroll") for (int p_ = 0; p_ < 4; ++p_) {   \
      uint32 t0_, t1_;                                   \
      PKMUL(t0_, Ei2, (FH_).u[p_])                       \
      PKMUL(t1_, Eip2, (PH_).u[p_])                      \
      PKMAX(t0_, t0_, t1_)                               \
      (AF).u[p_] = t0_ & (MSK_).u[p_];                   \
    }                                                    \
  }

#define WGEN(S)                      \
  WGEN1(S.AF0, S.FH0, S.PH0, S.M0)   \
  WGEN1(S.AF1, S.FH1, S.PH1, S.M1)

#define LUTREAD(S)                          \
  S.M0.v = lut[(S.w0 >> kq8) & 0xFF];       \
  S.M1.v = lut[(S.w1 >> kq8) & 0xFF];

#define PFETCH(S, C)                                      \
  {                                                       \
    const char* f_ = fbase + (C) * 128 + kq16;            \
    const char* p_ = pbase + (C) * 128 + kq16;            \
    S.FH0.v = *(const uint4*)(f_);                        \
    S.FH1.v = *(const uint4*)(f_ + 64);                   \
    S.PH0.v = *(const uint4*)(p_);                        \
    S.PH1.v = *(const uint4*)(p_ + 64);                   \
    S.w0 = adjp[iRb + (C) * 2];                           \
    S.w1 = adjp[iRb + (C) * 2 + 1];                       \
  }

#define LOADB(BR, C)                                      \
  {                                                       \
    const char* g_ = gbase + (size_t)(C) * 16384;         \
    _Pragma("unroll") for (int q_ = 0; q_ < 8; ++q_)      \
      BR[q_] = *(const f16x8*)(g_ + q_ * 1024);           \
  }

#define DOMFMA(S, BX)                                                                  \
  _Pragma("unroll") for (int nt_ = 0; nt_ < 4; ++nt_) {                                \
    acc0[nt_] = __builtin_amdgcn_mfma_f32_16x16x32_f16(S.AF0.v, BX[2 * nt_], acc0[nt_], 0, 0, 0);     \
    acc1[nt_] = __builtin_amdgcn_mfma_f32_16x16x32_f16(S.AF1.v, BX[2 * nt_ + 1], acc1[nt_], 0, 0, 0); \
  }                                                                                    \
  accS0 = __builtin_amdgcn_mfma_f32_16x16x32_f16(S.AF0.v, onesv, accS0, 0, 0, 0);      \
  accS1 = __builtin_amdgcn_mfma_f32_16x16x32_f16(S.AF1.v, onesv, accS1, 0, 0, 0);

#define BODYF(C, SX, BX, SY)  \
  {                           \
    DOMFMA(SX, BX)            \
    LUTREAD(SY)               \
    WGEN(SY)                  \
    LOADB(BX, (C) + 2)        \
    PFETCH(SX, (C) + 2)       \
  }

__global__ __launch_bounds__(256, 2) void k_attn(
    const _Float16* __restrict__ pTf,
    const float* __restrict__ ei,
    const _Float16* __restrict__ Fht,
    const _Float16* __restrict__ Pht,
    const unsigned int* __restrict__ adjp,
    float* __restrict__ out) {
  __shared__ uint4 lut[256];  // adj-bit-pair -> f16x2 mask words
  {
    const int tb = threadIdx.x;
    const uint32 m0 = ((tb & 1) ? 0xFFFFu : 0u) | ((tb & 2) ? 0xFFFF0000u : 0u);
    const uint32 m1 = ((tb & 4) ? 0xFFFFu : 0u) | ((tb & 8) ? 0xFFFF0000u : 0u);
    const uint32 m2 = ((tb & 16) ? 0xFFFFu : 0u) | ((tb & 32) ? 0xFFFF0000u : 0u);
    const uint32 m3 = ((tb & 64) ? 0xFFFFu : 0u) | ((tb & 128) ? 0xFFFF0000u : 0u);
    lut[tb] = make_uint4(m0, m1, m2, m3);
  }
  __syncthreads();  // write-once LUT; read-only afterwards

  const int t = threadIdx.x, lane = t & 63, wave = t >> 6;
  const int pay = (blockIdx.x & 7) * 64 + (blockIdx.x >> 3);
  const int bdh = pay >> 5;
  const int ig = pay & 31;
  const int b = bdh >> 1, dh = bdh & 1;
  const int i0 = ig * 64 + wave * 16;
  const int kq = lane >> 4;
  const int kq8 = kq * 8;
  const int kq16 = kq * 16;
  const int iR = i0 + (lane & 15);
  const int iRb = iR * 64;
  const float eiv = ei[(size_t)b * V + iR];
  const float Eif = __expf(eiv);
  const float Eipf = __expf(0.2f * eiv);
  const uint32 Ei2 = pk2(Eif, Eif);
  const uint32 Eip2 = pk2(Eipf, Eipf);
  const char* fbase = (const char*)(Fht + (size_t)b * V);
  const char* pbase = (const char*)(Pht + (size_t)b * V);
  const size_t fb0 = ((size_t)b * 32) * 16384 + (size_t)dh * 8192;
  const char* gbase = (const char*)pTf + fb0 + lane * 16;

  union { uint32 u[4]; f16x8 v; } ones_;
  ones_.u[0] = ones_.u[1] = ones_.u[2] = ones_.u[3] = 0x3C003C00u;
  const f16x8 onesv = ones_.v;

  f32x4 acc0[4], acc1[4];
#pragma unroll
  for (int nt = 0; nt < 4; ++nt) {
    acc0[nt] = (f32x4){0.f, 0.f, 0.f, 0.f};
    acc1[nt] = (f32x4){0.f, 0.f, 0.f, 0.f};
  }
  f32x4 accS0 = (f32x4){0.f, 0.f, 0.f, 0.f};
  f32x4 accS1 = (f32x4){0.f, 0.f, 0.f, 0.f};

  f16x8 bA[8], bB[8];
  PFS sA, sB;

  LOADB(bA, 0)
  LOADB(bB, 1)
  PFETCH(sA, 0)
  PFETCH(sB, 1)
  LUTREAD(sA)
  WGEN(sA)

  for (int c2 = 0; c2 < 15; ++c2) {
    const int c = c2 * 2;
    BODYF(c, sA, bA, sB)
    BODYF(c + 1, sB, bB, sA)
  }
  {
    DOMFMA(sA, bA)
    LUTREAD(sB)
    WGEN(sB)
  }
  { DOMFMA(sB, bB) }

  float* ob = out + ((size_t)b * V + i0) * D + dh * 64 + (lane & 15);
#pragma unroll
  for (int r = 0; r < 4; ++r) {
    const float inv_ = 1.0f / (accS0[r] + accS1[r]);
#pragma unroll
    for (int nt = 0; nt < 4; ++nt) {
      const float v = (acc0[nt][r] + acc1[nt][r]) * inv_;
      ob[(size_t)(kq * 4 + r) * D + nt * 16] = fmaxf(v, 0.f);
    }
  }
}

extern "C" void kernel_launch(void* const* d_in, const int* in_sizes, int n_in,
                              void* d_out, int out_size, void* d_ws, size_t ws_size,
                              hipStream_t stream) {
  const float* x = (const float*)d_in[0];
  const int* adj = (const int*)d_in[1];
  const float* W = (const float*)d_in[2];
  const float* a = (const float*)d_in[3];
  float* out = (float*)d_out;

  char* ws = (char*)d_ws;
  _Float16* pTf = (_Float16*)ws;                                   // 4 MB
  float* ei = (float*)(ws + (4u << 20));                           // 64 KB
  _Float16* Fh = (_Float16*)(ws + (4u << 20) + 65536);             // 32 KB
  _Float16* Ph = (_Float16*)(ws + (4u << 20) + 98304);             // 32 KB
  unsigned int* adjp = (unsigned int*)(ws + (4u << 20) + 131072);  // 512 KB
  float* vL = (float*)(ws + (4u << 20) + 131072 + 524288);         // 1 KB
  float* vR = (float*)(ws + (4u << 20) + 131072 + 524288 + 1024);  // 1 KB

  k_pack<<<dim3(V + 1), dim3(256), 0, stream>>>(adj, W, a, adjp, vL, vR);
  k_proj<<<dim3(BATCH * (V / 32)), dim3(256), 0, stream>>>(x, W, vL, vR, pTf, ei, Fh, Ph);
  k_attn<<<dim3(BATCH * 2 * (V / 64)), dim3(256), 0, stream>>>(pTf, ei, Fh, Ph, adjp, out);
}

// Round 11
// 54.691 us; speedup vs baseline: 1.0769x; 1.0769x over previous
//
#include <hip/hip_runtime.h>
#include <hip/hip_bf16.h>

#define BATCH 8
#define V 2048
#define H 256
#define D 128

typedef __attribute__((ext_vector_type(8))) _Float16 f16x8;
typedef __attribute__((ext_vector_type(4))) float f32x4;
typedef unsigned int uint32;

static __device__ __forceinline__ uint32 pk2(float lo, float hi) {
  __fp16 __attribute__((ext_vector_type(2))) h = __builtin_amdgcn_cvt_pkrtz(lo, hi);
  uint32 u;
  __builtin_memcpy(&u, &h, 4);
  return u;
}

// -------- K_pack: adj -> bitmask words, TRANSPOSED [jw][i]; blk==V: vL/vR = W^T a --------
__global__ __launch_bounds__(256) void k_pack(const int* __restrict__ adj,
                                              const float* __restrict__ W,
                                              const float* __restrict__ a,
                                              unsigned int* __restrict__ pkT,
                                              float* __restrict__ vL,
                                              float* __restrict__ vR) {
  const int blk = blockIdx.x;
  if (blk < V) {
    const int w = threadIdx.x >> 6, lane = threadIdx.x & 63;
    const int* row = adj + (size_t)blk * V;
#pragma unroll
    for (int it = 0; it < 8; ++it) {
      const int j = it * 256 + w * 64 + lane;
      unsigned long long m = __ballot(row[j] != 0);
      if (lane < 2) {
        const int jw = it * 8 + w * 2 + lane;
        pkT[(size_t)jw * V + blk] = (unsigned int)(m >> (lane * 32));
      }
    }
  } else {
    const int h = threadIdx.x;  // 0..255
    float sL = 0.f, sR = 0.f;
    for (int d = 0; d < D; ++d) {
      const float wv = W[(size_t)d * H + h];
      sL += wv * a[d];
      sR += wv * a[D + d];
    }
    vL[h] = sL;
    vR[h] = sR;
  }
}

// -------- K_proj: p = x @ W^T via f16 MFMA (fp32 acc); e from x.(W^T a) in fp32;
//          f16 fragment store to pTf (unchanged from R10) --------
#define DOT4(s, xv, vv) \
  s += (xv).x * (vv).x + (xv).y * (vv).y + (xv).z * (vv).z + (xv).w * (vv).w;

__global__ __launch_bounds__(256, 2) void k_proj(const float* __restrict__ x,
                                                 const float* __restrict__ W,
                                                 const float* __restrict__ vL,
                                                 const float* __restrict__ vR,
                                                 _Float16* __restrict__ pTf,
                                                 float* __restrict__ ei,
                                                 _Float16* __restrict__ Fh,
                                                 _Float16* __restrict__ Ph) {
  __shared__ _Float16 st[128][52];  // 13 KB
  const int t = threadIdx.x, lane = t & 63, wave = t >> 6;
  const int b = blockIdx.x >> 6;
  const int j0 = (blockIdx.x & 63) * 32;
  const int kq = lane >> 4, l15 = lane & 15;

  const float* wrow0 = W + (size_t)(wave * 32 + l15) * H + kq * 8;      // dt0
  const float* wrow1 = wrow0 + 16 * H;                                   // dt1
  const float* xrow0 = x + ((size_t)(b * V + j0 + l15)) * H + kq * 8;    // jt0
  const float* xrow1 = xrow0 + 16 * H;                                   // jt1
  const float* vLp = vL + kq * 8;
  const float* vRp = vR + kq * 8;

  f32x4 acc[2][2];
#pragma unroll
  for (int i_ = 0; i_ < 2; ++i_)
#pragma unroll
    for (int j_ = 0; j_ < 2; ++j_) acc[i_][j_] = (f32x4){0.f, 0.f, 0.f, 0.f};
  float eL0 = 0.f, eL1 = 0.f, eR0 = 0.f, eR1 = 0.f;

  typedef union { uint32 u[4]; f16x8 v; } AFu_;
#pragma unroll
  for (int ks = 0; ks < 8; ++ks) {
    const int ho = ks * 32;
    const float4 w0a = *(const float4*)(wrow0 + ho), w0b = *(const float4*)(wrow0 + ho + 4);
    const float4 w1a = *(const float4*)(wrow1 + ho), w1b = *(const float4*)(wrow1 + ho + 4);
    const float4 x0a = *(const float4*)(xrow0 + ho), x0b = *(const float4*)(xrow0 + ho + 4);
    const float4 x1a = *(const float4*)(xrow1 + ho), x1b = *(const float4*)(xrow1 + ho + 4);
    AFu_ aw0, aw1, bx0, bx1;
    aw0.u[0] = pk2(w0a.x, w0a.y); aw0.u[1] = pk2(w0a.z, w0a.w);
    aw0.u[2] = pk2(w0b.x, w0b.y); aw0.u[3] = pk2(w0b.z, w0b.w);
    aw1.u[0] = pk2(w1a.x, w1a.y); aw1.u[1] = pk2(w1a.z, w1a.w);
    aw1.u[2] = pk2(w1b.x, w1b.y); aw1.u[3] = pk2(w1b.z, w1b.w);
    bx0.u[0] = pk2(x0a.x, x0a.y); bx0.u[1] = pk2(x0a.z, x0a.w);
    bx0.u[2] = pk2(x0b.x, x0b.y); bx0.u[3] = pk2(x0b.z, x0b.w);
    bx1.u[0] = pk2(x1a.x, x1a.y); bx1.u[1] = pk2(x1a.z, x1a.w);
    bx1.u[2] = pk2(x1b.x, x1b.y); bx1.u[3] = pk2(x1b.z, x1b.w);
    acc[0][0] = __builtin_amdgcn_mfma_f32_16x16x32_f16(aw0.v, bx0.v, acc[0][0], 0, 0, 0);
    acc[0][1] = __builtin_amdgcn_mfma_f32_16x16x32_f16(aw0.v, bx1.v, acc[0][1], 0, 0, 0);
    acc[1][0] = __builtin_amdgcn_mfma_f32_16x16x32_f16(aw1.v, bx0.v, acc[1][0], 0, 0, 0);
    acc[1][1] = __builtin_amdgcn_mfma_f32_16x16x32_f16(aw1.v, bx1.v, acc[1][1], 0, 0, 0);
    if (wave == 0) {
      const float4 vla = *(const float4*)(vLp + ho), vlb = *(const float4*)(vLp + ho + 4);
      const float4 vra = *(const float4*)(vRp + ho), vrb = *(const float4*)(vRp + ho + 4);
      DOT4(eL0, x0a, vla) DOT4(eL0, x0b, vlb)
      DOT4(eL1, x1a, vla) DOT4(eL1, x1b, vlb)
      DOT4(eR0, x0a, vra) DOT4(eR0, x0b, vrb)
      DOT4(eR1, x1a, vra) DOT4(eR1, x1b, vrb)
    }
  }

  if (wave == 0) {
    eL0 += __shfl_xor(eL0, 16, 64); eL0 += __shfl_xor(eL0, 32, 64);
    eL1 += __shfl_xor(eL1, 16, 64); eL1 += __shfl_xor(eL1, 32, 64);
    eR0 += __shfl_xor(eR0, 16, 64); eR0 += __shfl_xor(eR0, 32, 64);
    eR1 += __shfl_xor(eR1, 16, 64); eR1 += __shfl_xor(eR1, 32, 64);
    if (lane < 16) {
      const size_t r0 = (size_t)b * V + j0 + lane;
      ei[r0] = eL0;
      Fh[r0] = (_Float16)__expf(eR0);
      Ph[r0] = (_Float16)__expf(0.2f * eR0);
      const size_t r1 = r0 + 16;
      ei[r1] = eL1;
      Fh[r1] = (_Float16)__expf(eR1);
      Ph[r1] = (_Float16)__expf(0.2f * eR1);
    }
  }

#pragma unroll
  for (int t_ = 0; t_ < 2; ++t_)
#pragma unroll
    for (int jt = 0; jt < 2; ++jt)
#pragma unroll
      for (int r = 0; r < 4; ++r)
        st[(wave * 2 + t_) * 16 + kq * 4 + r][jt * 16 + l15] = (_Float16)acc[t_][jt][r];
  __syncthreads();

  const int c = (blockIdx.x & 63) >> 1;
  const int ks = blockIdx.x & 1;
  const int g = t >> 6;
#pragma unroll
  for (int ff = 0; ff < 2; ++ff) {
    const int dt = ff * 4 + g;
    const int dR = dt * 16 + l15;
    const int jc = kq * 8;
    union { unsigned long long ll[2]; f16x8 v; } vv_;
    vv_.ll[0] = *(const unsigned long long*)&st[dR][jc];
    vv_.ll[1] = *(const unsigned long long*)&st[dR][jc + 4];
    *(f16x8*)((char*)pTf +
              (((((size_t)b * 32 + c) * 8 + dt) * 2 + ks) * 64 + lane) * 16) = vv_.v;
  }
}

// -------- K_attn: wave = 32 i (2 groups) x 32 d (2 nt) -> halves B-load traffic --------
// per chunk/wave: 4 B-frag loads (4 KB contiguous), 8 PV MFMA + 4 rowsum MFMA,
// all independent acc chains; af pipelined 1 body ahead; no LDS data sharing.

typedef union { uint4 v; uint32 u[4]; } U4;
typedef union { uint32 u[4]; f16x8 v; } AFu;
struct PFS {
  U4 FH0, FH1, PH0, PH1;  // F/P tables, shared by both i-groups
  uint32 w[2][2];         // adj words [ig][ks]
  AFu AF[2][2];           // A fragments [ig][ks]
};

#define PKMUL(d, a, b) asm("v_pk_mul_f16 %0, %1, %2" : "=v"(d) : "v"(a), "v"(b));
#define PKMAX(d, a, b) asm("v_pk_max_f16 %0, %1, %2" : "=v"(d) : "v"(a), "v"(b));

#define WGEN(S)                                                        \
  _Pragma("unroll") for (int ig_ = 0; ig_ < 2; ++ig_) {                \
    const uint32 E2_ = Ei2g[ig_], EP2_ = Eip2g[ig_];                   \
    _Pragma("unroll") for (int ks_ = 0; ks_ < 2; ++ks_) {              \
      U4 M_;                                                           \
      M_.v = lut[((S).w[ig_][ks_] >> kq8) & 0xFF];                     \
      const U4& FH_ = ks_ ? (S).FH1 : (S).FH0;                         \
      const U4& PH_ = ks_ ? (S).PH1 : (S).PH0;                         \
      _Pragma("unroll") for (int p_ = 0; p_ < 4; ++p_) {               \
        uint32 t0_, t1_;                                               \
        PKMUL(t0_, E2_, FH_.u[p_])                                     \
        PKMUL(t1_, EP2_, PH_.u[p_])                                    \
        PKMAX(t0_, t0_, t1_)                                           \
        (S).AF[ig_][ks_].u[p_] = t0_ & M_.u[p_];                       \
      }                                                                \
    }                                                                  \
  }

#define PFETCH(S, C)                                       \
  {                                                        \
    const char* f_ = fbase + (C) * 128 + kq16;             \
    const char* p_ = pbase + (C) * 128 + kq16;             \
    (S).FH0.v = *(const uint4*)(f_);                       \
    (S).FH1.v = *(const uint4*)(f_ + 64);                  \
    (S).PH0.v = *(const uint4*)(p_);                       \
    (S).PH1.v = *(const uint4*)(p_ + 64);                  \
    (S).w[0][0] = adjpT[(size_t)((C) * 2) * V + iR0];      \
    (S).w[0][1] = adjpT[(size_t)((C) * 2 + 1) * V + iR0];  \
    (S).w[1][0] = adjpT[(size_t)((C) * 2) * V + iR1];      \
    (S).w[1][1] = adjpT[(size_t)((C) * 2 + 1) * V + iR1];  \
  }

#define LOADB(BR, C)                                      \
  {                                                       \
    const char* g_ = gbase + (size_t)(C) * 16384;         \
    _Pragma("unroll") for (int q_ = 0; q_ < 4; ++q_)      \
      BR[q_] = *(const f16x8*)(g_ + q_ * 1024);           \
  }

#define DOMFMA(S, BX)                                                          \
  _Pragma("unroll") for (int ig_ = 0; ig_ < 2; ++ig_)                          \
    _Pragma("unroll") for (int nt_ = 0; nt_ < 2; ++nt_)                        \
      _Pragma("unroll") for (int ks_ = 0; ks_ < 2; ++ks_)                      \
        acc[ig_][nt_][ks_] = __builtin_amdgcn_mfma_f32_16x16x32_f16(           \
            (S).AF[ig_][ks_].v, BX[nt_ * 2 + ks_], acc[ig_][nt_][ks_], 0, 0, 0); \
  _Pragma("unroll") for (int ig_ = 0; ig_ < 2; ++ig_)                          \
    _Pragma("unroll") for (int ks_ = 0; ks_ < 2; ++ks_)                        \
      accS[ig_][ks_] = __builtin_amdgcn_mfma_f32_16x16x32_f16(                 \
          (S).AF[ig_][ks_].v, onesv, accS[ig_][ks_], 0, 0, 0);

#define BODYF(C, SX, BX, SY)   \
  {                            \
    DOMFMA(SX, BX)             \
    WGEN(SY)                   \
    LOADB(BX, (C) + 2)         \
    PFETCH(SX, (C) + 2)        \
  }

__global__ __launch_bounds__(256, 2) void k_attn(
    const _Float16* __restrict__ pTf,
    const float* __restrict__ ei,
    const _Float16* __restrict__ Fht,
    const _Float16* __restrict__ Pht,
    const unsigned int* __restrict__ adjpT,
    float* __restrict__ out) {
  __shared__ uint4 lut[256];  // adj-byte -> f16x2 mask words
  {
    const int tb = threadIdx.x;
    const uint32 m0 = ((tb & 1) ? 0xFFFFu : 0u) | ((tb & 2) ? 0xFFFF0000u : 0u);
    const uint32 m1 = ((tb & 4) ? 0xFFFFu : 0u) | ((tb & 8) ? 0xFFFF0000u : 0u);
    const uint32 m2 = ((tb & 16) ? 0xFFFFu : 0u) | ((tb & 32) ? 0xFFFF0000u : 0u);
    const uint32 m3 = ((tb & 64) ? 0xFFFFu : 0u) | ((tb & 128) ? 0xFFFF0000u : 0u);
    lut[tb] = make_uint4(m0, m1, m2, m3);
  }
  __syncthreads();  // write-once LUT; read-only afterwards

  const int t = threadIdx.x, lane = t & 63, wave = t >> 6;
  const int ih = wave >> 1;  // i-half of block (0/1)
  const int dq = wave & 1;   // d-quarter of dh-half (0/1)
  // bijective XCD chunk swizzle (nwg=512, 64 per XCD)
  const int pay = (blockIdx.x & 7) * 64 + (blockIdx.x >> 3);
  const int bdh = pay >> 4;   // 0..31
  const int itl = pay & 15;
  const int b = bdh >> 2, dh = (bdh >> 1) & 1;
  const int it = ((bdh & 1) << 4) | itl;  // 0..31
  const int i0b = it * 64;
  const int kq = lane >> 4;
  const int kq8 = kq * 8;
  const int kq16 = kq * 16;
  const int l15 = lane & 15;
  const int ibase = i0b + ih * 32;
  const int iR0 = ibase + l15;
  const int iR1 = iR0 + 16;

  const float eiv0 = ei[(size_t)b * V + iR0];
  const float eiv1 = ei[(size_t)b * V + iR1];
  uint32 Ei2g[2], Eip2g[2];
  {
    const float e0 = __expf(eiv0), e1 = __expf(eiv1);
    const float p0 = __expf(0.2f * eiv0), p1 = __expf(0.2f * eiv1);
    Ei2g[0] = pk2(e0, e0); Ei2g[1] = pk2(e1, e1);
    Eip2g[0] = pk2(p0, p0); Eip2g[1] = pk2(p1, p1);
  }
  const char* fbase = (const char*)(Fht + (size_t)b * V);
  const char* pbase = (const char*)(Pht + (size_t)b * V);
  const size_t fb0 = ((size_t)b * 32) * 16384 + (size_t)dh * 8192;
  const char* gbase = (const char*)pTf + fb0 + dq * 4096 + lane * 16;

  union { uint32 u[4]; f16x8 v; } ones_;
  ones_.u[0] = ones_.u[1] = ones_.u[2] = ones_.u[3] = 0x3C003C00u;
  const f16x8 onesv = ones_.v;

  f32x4 acc[2][2][2];  // [ig][nt][ks]
#pragma unroll
  for (int a_ = 0; a_ < 2; ++a_)
#pragma unroll
    for (int b_ = 0; b_ < 2; ++b_)
#pragma unroll
      for (int c_ = 0; c_ < 2; ++c_) acc[a_][b_][c_] = (f32x4){0.f, 0.f, 0.f, 0.f};
  f32x4 accS[2][2];  // [ig][ks]
#pragma unroll
  for (int a_ = 0; a_ < 2; ++a_)
#pragma unroll
    for (int c_ = 0; c_ < 2; ++c_) accS[a_][c_] = (f32x4){0.f, 0.f, 0.f, 0.f};

  f16x8 bA[4], bB[4];
  PFS sA, sB;

  // prologue
  LOADB(bA, 0)
  LOADB(bB, 1)
  PFETCH(sA, 0)
  PFETCH(sB, 1)
  WGEN(sA)

  for (int c2 = 0; c2 < 15; ++c2) {
    const int c = c2 * 2;
    BODYF(c, sA, bA, sB)
    BODYF(c + 1, sB, bB, sA)
  }
  // tail: chunk 30 (af for 31 built, no more loads), chunk 31
  {
    DOMFMA(sA, bA)
    WGEN(sB)
  }
  { DOMFMA(sB, bB) }

  // epilogue: rowsums are in accS (ones-column MFMA), lane-aligned
  float* ob = out + ((size_t)b * V + ibase) * D + dh * 64 + dq * 32 + l15;
#pragma unroll
  for (int ig = 0; ig < 2; ++ig) {
#pragma unroll
    for (int r = 0; r < 4; ++r) {
      const float inv_ = 1.0f / (accS[ig][0][r] + accS[ig][1][r]);
#pragma unroll
      for (int nt = 0; nt < 2; ++nt) {
        const float v = (acc[ig][nt][0][r] + acc[ig][nt][1][r]) * inv_;
        ob[(size_t)(ig * 16 + kq * 4 + r) * D + nt * 16] = fmaxf(v, 0.f);
      }
    }
  }
}

extern "C" void kernel_launch(void* const* d_in, const int* in_sizes, int n_in,
                              void* d_out, int out_size, void* d_ws, size_t ws_size,
                              hipStream_t stream) {
  const float* x = (const float*)d_in[0];
  const int* adj = (const int*)d_in[1];
  const float* W = (const float*)d_in[2];
  const float* a = (const float*)d_in[3];
  float* out = (float*)d_out;

  char* ws = (char*)d_ws;
  _Float16* pTf = (_Float16*)ws;                                   // 4 MB
  float* ei = (float*)(ws + (4u << 20));                           // 64 KB
  _Float16* Fh = (_Float16*)(ws + (4u << 20) + 65536);             // 32 KB
  _Float16* Ph = (_Float16*)(ws + (4u << 20) + 98304);             // 32 KB
  unsigned int* adjpT = (unsigned int*)(ws + (4u << 20) + 131072); // 512 KB
  float* vL = (float*)(ws + (4u << 20) + 131072 + 524288);         // 1 KB
  float* vR = (float*)(ws + (4u << 20) + 131072 + 524288 + 1024);  // 1 KB

  k_pack<<<dim3(V + 1), dim3(256), 0, stream>>>(adj, W, a, adjpT, vL, vR);
  k_proj<<<dim3(BATCH * (V / 32)), dim3(256), 0, stream>>>(x, W, vL, vR, pTf, ei, Fh, Ph);
  k_attn<<<dim3(BATCH * 2 * (V / 64)), dim3(256), 0, stream>>>(pTf, ei, Fh, Ph, adjpT, out);
}